// Round 4
// baseline (245.430 us; speedup 1.0000x reference)
//
#include <hip/hip_runtime.h>

// Biquad DF2T over [B=512, T=48000] fp32, per-channel coeffs.
// One block per channel, 512 threads, 4 stages of 12000 samples.
// Per stage:
//   fill:   coalesced float4 global->LDS (swizzled slots, conflict-free b128)
//   (prefetch next stage's x into registers -- overlaps with everything below)
//   local:  each of 500 threads: zero-state response over its 24-sample row
//           (row loaded to regs once, reused by replay)
//   scan:   per-wave shfl_up inclusive scan of affine (Phi, w) transforms
//           + one LDS round for the 8 wave aggregates      -> true init state
//   replay: exact reference arithmetic from init state, y -> LDS row slots
//   wb:     coalesced float4 LDS->global
// 4 barriers/stage. x read once, y written once, no global scratch.

#define B_CH   512
#define T_LEN  48000
#define NSTAGE 4
#define STAGE  12000
#define NACT   500
#define L      24
#define NF4    (STAGE / 4)   // 3000 float4 per stage
#define ROWSL  8             // float4 slots per row (6 used, swizzled)

struct Aff { float p00, p01, p10, p11, w0, w1; };

__device__ __forceinline__ Aff aff_comp(const Aff& hi, const Aff& lo) {
    // apply lo first, then hi:  s' = Phi_hi*(Phi_lo*s + w_lo) + w_hi
    Aff r;
    r.p00 = hi.p00*lo.p00 + hi.p01*lo.p10;
    r.p01 = hi.p00*lo.p01 + hi.p01*lo.p11;
    r.p10 = hi.p10*lo.p00 + hi.p11*lo.p10;
    r.p11 = hi.p10*lo.p01 + hi.p11*lo.p11;
    r.w0  = hi.p00*lo.w0  + hi.p01*lo.w1  + hi.w0;
    r.w1  = hi.p10*lo.w0  + hi.p11*lo.w1  + hi.w1;
    return r;
}

__device__ __forceinline__ Aff aff_shfl_up(const Aff& a, int delta) {
    Aff r;
    r.p00 = __shfl_up(a.p00, delta, 64);
    r.p01 = __shfl_up(a.p01, delta, 64);
    r.p10 = __shfl_up(a.p10, delta, 64);
    r.p11 = __shfl_up(a.p11, delta, 64);
    r.w0  = __shfl_up(a.w0,  delta, 64);
    r.w1  = __shfl_up(a.w1,  delta, 64);
    return r;
}

__global__ __launch_bounds__(512, 4) void k_biquad_fused(
    const float* __restrict__ x,
    const float* __restrict__ b0, const float* __restrict__ b1,
    const float* __restrict__ b2,
    const float* __restrict__ a1, const float* __restrict__ a2,
    float* __restrict__ y)
{
    __shared__ float4 xl[NACT * ROWSL];   // 4000 float4 = 62.5 KB
    __shared__ Aff    agg[8];

    const int b    = blockIdx.x;
    const int t    = threadIdx.x;
    const int lane = t & 63;
    const int wv   = t >> 6;

    const float A1 = a1[b], A2 = a2[b];
    const float B0 = b0[b], B1 = b1[b], B2 = b2[b];
    // y-eliminated state form: z1' = c1*x - a1*z1 + z2 ; z2' = c2*x - a2*z1
    const float c1 = B1 - A1 * B0;
    const float c2 = B2 - A2 * B0;

    // G = Phi = A^L, A = [[-a1,1],[-a2,0]] (binary exponentiation)
    float G00, G01, G10, G11;
    {
        float m00 = -A1, m01 = 1.f, m10 = -A2, m11 = 0.f;
        float f00 = 1.f, f01 = 0.f, f10 = 0.f, f11 = 1.f;
        int e = L;
        while (e) {
            if (e & 1) {
                float t00 = f00*m00 + f01*m10, t01 = f00*m01 + f01*m11;
                float t10 = f10*m00 + f11*m10, t11 = f10*m01 + f11*m11;
                f00 = t00; f01 = t01; f10 = t10; f11 = t11;
            }
            e >>= 1;
            if (!e) break;
            float s00 = m00*m00 + m01*m10, s01 = m00*m01 + m01*m11;
            float s10 = m10*m00 + m11*m10, s11 = m10*m01 + m11*m11;
            m00 = s00; m01 = s01; m10 = s10; m11 = s11;
        }
        G00 = f00; G01 = f01; G10 = f10; G11 = f11;
    }

    // fill/writeback mapping (same for all stages): global float4 g -> LDS slot
    int  ldsIdx[6], gOff[6];
    bool gval[6];
    #pragma unroll
    for (int p = 0; p < 6; ++p) {
        const int g = t + 512 * p;
        gval[p]   = (g < NF4);
        const int own = g / 6;
        const int j   = g - own * 6;
        ldsIdx[p] = own * ROWSL + ((j + own) & 7);
        gOff[p]   = 4 * g;
    }

    const float* xb = x + (size_t)b * T_LEN;
    float*       yb = y + (size_t)b * T_LEN;

    // preload stage 0 into registers
    float4 r[6];
    #pragma unroll
    for (int p = 0; p < 6; ++p) if (gval[p]) r[p] = *(const float4*)(xb + gOff[p]);

    float cz1 = 0.f, cz2 = 0.f;   // inter-stage carry state

    for (int s = 0; s < NSTAGE; ++s) {
        // ---- fill: registers -> swizzled LDS
        #pragma unroll
        for (int p = 0; p < 6; ++p) if (gval[p]) xl[ldsIdx[p]] = r[p];

        // ---- prefetch next stage (waits consumed next iteration)
        float4 rn[6];
        if (s + 1 < NSTAGE) {
            const float* xn = xb + (s + 1) * STAGE;
            #pragma unroll
            for (int p = 0; p < 6; ++p) if (gval[p]) rn[p] = *(const float4*)(xn + gOff[p]);
        }
        __syncthreads();                              // B1: fill visible

        // ---- own row -> registers (conflict-free b128), local zero-state pass
        float xr[L];
        Aff S;
        if (t < NACT) {
            #pragma unroll
            for (int j = 0; j < 6; ++j) {
                const float4 v = xl[t * ROWSL + ((j + t) & 7)];
                xr[4*j] = v.x; xr[4*j+1] = v.y; xr[4*j+2] = v.z; xr[4*j+3] = v.w;
            }
            float z1 = 0.f, z2 = 0.f;
            #pragma unroll
            for (int i = 0; i < L; ++i) {
                const float xn = xr[i];
                const float nz1 = c1 * xn + z2 - A1 * z1;
                z2 = c2 * xn - A2 * z1;
                z1 = nz1;
            }
            S.p00 = G00; S.p01 = G01; S.p10 = G10; S.p11 = G11;
            S.w0 = z1; S.w1 = z2;
        } else {
            S.p00 = 1.f; S.p01 = 0.f; S.p10 = 0.f; S.p11 = 1.f;
            S.w0 = 0.f; S.w1 = 0.f;
        }

        // ---- per-wave inclusive scan (no barriers, no LDS)
        #pragma unroll
        for (int off = 1; off < 64; off <<= 1) {
            const Aff up = aff_shfl_up(S, off);
            if (lane >= off) S = aff_comp(S, up);
        }
        const Aff Sprev = aff_shfl_up(S, 1);          // S of lane-1 (garbage @ lane 0)
        if (lane == 63) agg[wv] = S;
        __syncthreads();                              // B2: aggregates visible

        // ---- compose wave prefixes (broadcast LDS reads, identical per thread)
        Aff acc;  acc.p00 = 1.f; acc.p01 = 0.f; acc.p10 = 0.f; acc.p11 = 1.f;
        acc.w0 = 0.f; acc.w1 = 0.f;
        Aff Wprev = acc;
        #pragma unroll
        for (int wi = 0; wi < 8; ++wi) {
            if (wi == wv) Wprev = acc;
            acc = aff_comp(agg[wi], acc);
        }
        const Aff Wall = acc;

        const Aff X = (lane == 0) ? Wprev : aff_comp(Sprev, Wprev);
        float z1 = X.p00 * cz1 + X.p01 * cz2 + X.w0;
        float z2 = X.p10 * cz1 + X.p11 * cz2 + X.w1;
        {
            const float n1 = Wall.p00 * cz1 + Wall.p01 * cz2 + Wall.w0;
            const float n2 = Wall.p10 * cz1 + Wall.p11 * cz2 + Wall.w1;
            cz1 = n1; cz2 = n2;
        }

        // ---- replay from true init state (reference arithmetic), y -> LDS
        if (t < NACT) {
            #pragma unroll
            for (int j = 0; j < 6; ++j) {
                float4 o;
                float* op = &o.x;
                #pragma unroll
                for (int q = 0; q < 4; ++q) {
                    const float xn = xr[4*j + q];
                    const float yn = B0 * xn + z1;
                    op[q] = yn;
                    const float nz1 = B1 * xn - A1 * yn + z2;
                    z2 = B2 * xn - A2 * yn;
                    z1 = nz1;
                }
                xl[t * ROWSL + ((j + t) & 7)] = o;
            }
        }
        __syncthreads();                              // B3: y rows visible

        // ---- writeback: swizzled LDS -> coalesced global
        float* ys = yb + s * STAGE;
        #pragma unroll
        for (int p = 0; p < 6; ++p)
            if (gval[p]) *(float4*)(ys + gOff[p]) = xl[ldsIdx[p]];
        __syncthreads();                              // B4: LDS reusable

        #pragma unroll
        for (int p = 0; p < 6; ++p) r[p] = rn[p];
    }
}

extern "C" void kernel_launch(void* const* d_in, const int* in_sizes, int n_in,
                              void* d_out, int out_size, void* d_ws, size_t ws_size,
                              hipStream_t stream) {
    const float* x  = (const float*)d_in[0];
    const float* b0 = (const float*)d_in[1];
    const float* b1 = (const float*)d_in[2];
    const float* b2 = (const float*)d_in[3];
    const float* a1 = (const float*)d_in[4];
    const float* a2 = (const float*)d_in[5];
    float* y = (float*)d_out;

    k_biquad_fused<<<dim3(B_CH), dim3(512), 0, stream>>>(x, b0, b1, b2, a1, a2, y);
}